// Round 3
// baseline (681.338 us; speedup 1.0000x reference)
//
#include <hip/hip_runtime.h>
#include <hip/hip_bf16.h>
#include <stdint.h>

// Problem dims
#define M_DIM 8192
#define K_DIM 7168
#define N_DIM 2112          // 1536 + 512 + 64
#define N_PAD 2112          // 11 * 192 exactly -> no pad columns
#define NQ 1536
#define NKV 512
#define NPE 64
#define NGROUPS 12          // 1536 / 128

// GEMM geometry: 128x192 tile, 4 waves (2M x 2N), per-wave 64x96.
#define BM 128
#define BN 192
#define BK 64
#define SPLITK 2
#define KHALF (K_DIM / SPLITK)     // 3584
#define NHALVES (KHALF / 32)       // 112 half-tiles (32 k each)
#define MT (M_DIM / BM)            // 64
#define NT (N_DIM / BN)            // 11
#define NWG (MT * NT * SPLITK)     // 1408 = 8 * 176

typedef __bf16 bf16x8 __attribute__((ext_vector_type(8)));
typedef float f32x4 __attribute__((ext_vector_type(4)));
typedef unsigned short ushort8 __attribute__((ext_vector_type(8)));

__device__ __forceinline__ unsigned short f32_to_bf16(float f) {
    unsigned int u = __float_as_uint(f);
    u += 0x7fffu + ((u >> 16) & 1u);   // round-to-nearest-even
    return (unsigned short)(u >> 16);
}

__device__ __forceinline__ void gload16(const unsigned short* g, unsigned short* l) {
    __builtin_amdgcn_global_load_lds(
        (const __attribute__((address_space(1))) unsigned int*)g,
        (__attribute__((address_space(3))) unsigned int*)l, 16, 0, 0);
}

// raw barrier: NO implicit vmcnt(0) drain (unlike __syncthreads)
#define SBAR() do { __builtin_amdgcn_sched_barrier(0); \
    asm volatile("" ::: "memory"); \
    __builtin_amdgcn_s_barrier(); \
    __builtin_amdgcn_sched_barrier(0); } while (0)
#define VMCNT(n) asm volatile("s_waitcnt vmcnt(" #n ")" ::: "memory")

// ---------------------------------------------------------------------------
// Kernel 1: A fp32 -> bf16, elementwise, vectorized
// ---------------------------------------------------------------------------
__global__ __launch_bounds__(256) void cvt_a_kernel(
    const float* __restrict__ in, unsigned short* __restrict__ out, int n4)
{
    int idx = blockIdx.x * 256 + threadIdx.x;
    int stride = gridDim.x * 256;
    const float4* in4 = (const float4*)in;
    ushort4* out4 = (ushort4*)out;
    for (int i = idx; i < n4; i += stride) {
        float4 v = in4[i];
        ushort4 o;
        o.x = f32_to_bf16(v.x);
        o.y = f32_to_bf16(v.y);
        o.z = f32_to_bf16(v.z);
        o.w = f32_to_bf16(v.w);
        out4[i] = o;
    }
}

// ---------------------------------------------------------------------------
// Kernel 2: W [K][N] fp32 -> Bt [N_DIM][K] bf16 (tiled transpose + convert)
// ---------------------------------------------------------------------------
__global__ __launch_bounds__(256) void cvt_bt_kernel(
    const float* __restrict__ B, unsigned short* __restrict__ Bt)
{
    __shared__ float tile[64][33];
    const int n0 = blockIdx.x * 32;
    const int k0 = blockIdx.y * 64;
    const int t = threadIdx.x;
    const int tx = t & 31;
    const int ty = t >> 5;
#pragma unroll
    for (int i = 0; i < 8; ++i) {
        int kk = ty + i * 8;
        tile[kk][tx] = B[(size_t)(k0 + kk) * N_DIM + n0 + tx];
    }
    __syncthreads();
    const int n_idx = t >> 3;
    const int k8 = (t & 7) * 8;
    ushort8 o;
#pragma unroll
    for (int j = 0; j < 8; ++j)
        o[j] = f32_to_bf16(tile[k8 + j][n_idx]);
    *reinterpret_cast<ushort8*>(&Bt[(size_t)(n0 + n_idx) * K_DIM + k0 + k8]) = o;
}

// ---------------------------------------------------------------------------
// Kernel 3: bf16 MFMA GEMM — small-block / high-TLP schedule.
//   Tile 128x192, 256 threads (4 waves, 2M x 2N), per-wave 64x96 (acc 4x6).
//   LDS 52 KiB/block -> 3 blocks/CU (12 waves/CU) for cross-block overlap:
//     A = ring-2 half-tile slots (2 x [128][32] bf16, 8 KB)
//     B = ring-3 half-tile slots (3 x [192][32] bf16, 12 KB)
//   Half-tile g (32 k): read A slot g&1 (4 frags) + B slot g%3 (6 frags),
//   stage A(g+1) [2 gloads] + B(g+2) [3 gloads], barrier, 24 MFMA, then
//   boundary fence vmcnt(3) — the 3 newest (B(g+2)) stay in flight; never 0
//   until the final half. Swizzle (64-B rows, 4 chunks of 16 B):
//   phys_chunk = chunk ^ ((row>>1)&3), applied on global src AND ds_read.
// ---------------------------------------------------------------------------
__global__ __launch_bounds__(256, 3) void gemm8_kernel(
    const unsigned short* __restrict__ A,
    const unsigned short* __restrict__ Bt,
    unsigned short* __restrict__ C)       // [SPLITK][M][N_PAD] bf16
{
    __shared__ unsigned short sm[26624];   // 53248 B = 52 KiB

    const int tid  = threadIdx.x;
    const int lane = tid & 63;
    const int wave = tid >> 6;      // 0..3
    const int wr = wave >> 1;       // 0..1  (M)
    const int wc = wave & 1;        // 0..1  (N)

    // bijective XCD swizzle (NWG = 1408 divisible by 8)
    const int bid = blockIdx.x;
    const int swz = (bid & 7) * (NWG / 8) + (bid >> 3);
    const int z   = swz / (MT * NT);
    const int rmn = swz % (MT * NT);
    const int mt  = rmn & 63;        // M fastest
    const int nt  = rmn >> 6;
    const int m0 = mt * BM;
    const int n0 = nt * BN;
    const size_t kbase = (size_t)z * KHALF;

    // ---- staging: linear LDS dest (wave-uniform base), inv-swizzled source ----
    // dest lane layout: row = base_row + (lane>>2), chunk = lane&3 (16B chunks)
    // source chunk = (lane&3) ^ ((lane>>3)&3)   [= chunk ^ ((row>>1)&3)]
    const int csw = ((lane & 3) ^ ((lane >> 3) & 3)) * 8;   // shorts
    const unsigned short* aSrc0 = A + (size_t)(m0 + wave * 32 + (lane >> 2)) * K_DIM + kbase + csw;
    const unsigned short* aSrc1 = aSrc0 + (size_t)16 * K_DIM;
    const unsigned short* bSrc0 = Bt + (size_t)(n0 + wave * 48 + (lane >> 2)) * K_DIM + kbase + csw;
    const unsigned short* bSrc1 = bSrc0 + (size_t)16 * K_DIM;
    const unsigned short* bSrc2 = bSrc0 + (size_t)32 * K_DIM;

#define STAGE_A(h) do { unsigned short* _d = sm + ((h) & 1) * 4096 + wave * 1024; \
        gload16(aSrc0 + (size_t)(h) * 32, _d); \
        gload16(aSrc1 + (size_t)(h) * 32, _d + 512); } while (0)
#define STAGE_B(h, s) do { unsigned short* _d = sm + 8192 + (s) * 6144 + wave * 1536; \
        gload16(bSrc0 + (size_t)(h) * 32, _d); \
        gload16(bSrc1 + (size_t)(h) * 32, _d + 512); \
        gload16(bSrc2 + (size_t)(h) * 32, _d + 1024); } while (0)

    // ---- LDS read offsets (bytes); same XOR involution as the source ----
    const int ln15 = lane & 15;
    const int rdsw = ((lane >> 4) ^ ((ln15 >> 1) & 3)) * 16;
    const int aRd = (wr * 64 + ln15) * 64 + rdsw;   // within A slot
    const int bRd = (wc * 96 + ln15) * 64 + rdsw;   // within B slot
#define LDSV(off) (*reinterpret_cast<const bf16x8*>(reinterpret_cast<const char*>(sm) + (off)))

    f32x4 acc[4][6];
#pragma unroll
    for (int i = 0; i < 4; ++i)
#pragma unroll
        for (int j = 0; j < 6; ++j) acc[i][j] = (f32x4)0.0f;

    // ---- prologue: A(0), B(0), B(1); wait A(0)+B(0), keep B(1) in flight ----
    STAGE_A(0);
    STAGE_B(0, 0);
    STAGE_B(1, 1);
    VMCNT(3);
    SBAR();

    int bslot = 0;
    for (int g = 0; g < NHALVES; ++g) {
        const int aoff = (g & 1) * 8192;            // bytes
        const int boff = 16384 + bslot * 12288;     // bytes
        bf16x8 av[4], bv[6];
#pragma unroll
        for (int j = 0; j < 6; ++j)
            bv[j] = LDSV(boff + bRd + j * 1024);
#pragma unroll
        for (int i = 0; i < 4; ++i)
            av[i] = LDSV(aoff + aRd + i * 1024);

        // stages: A(g+1) then B(g+2) (order matters for the vmcnt(3) proof)
        if (g < NHALVES - 1) STAGE_A(g + 1);
        int nbs = bslot + 2; if (nbs >= 3) nbs -= 3;
        if (g < NHALVES - 2) STAGE_B(g + 2, nbs);

        SBAR();
        __builtin_amdgcn_s_setprio(1);
#pragma unroll
        for (int j = 0; j < 6; ++j)
#pragma unroll
            for (int i = 0; i < 4; ++i)
                acc[i][j] = __builtin_amdgcn_mfma_f32_16x16x32_bf16(
                    av[i], bv[j], acc[i][j], 0, 0, 0);
        __builtin_amdgcn_s_setprio(0);

        if (g < NHALVES - 1) {
            if (g < NHALVES - 2) { VMCNT(3); } else { VMCNT(0); }
            SBAR();
        }
        bslot = (bslot == 2) ? 0 : bslot + 1;
    }

    // Epilogue: C/D layout col = lane&15, row = (lane>>4)*4 + v  (m89/m91)
    unsigned short* Cz = C + (size_t)z * M_DIM * N_PAD;
    const int crow = (lane >> 4) * 4;
    const int ccol = lane & 15;
#pragma unroll
    for (int i = 0; i < 4; ++i) {
#pragma unroll
        for (int j = 0; j < 6; ++j) {
            const int gm = m0 + wr * 64 + i * 16 + crow;
            const int gn = n0 + wc * 96 + j * 16 + ccol;
            unsigned short* cp = Cz + (size_t)gm * N_PAD + gn;
#pragma unroll
            for (int v = 0; v < 4; ++v)
                cp[(size_t)v * N_PAD] = f32_to_bf16(acc[i][j][v]);
        }
    }
#undef STAGE_A
#undef STAGE_B
#undef LDSV
}

// ---------------------------------------------------------------------------
// Kernel 4: per-row epilogue. Reads both split-K bf16 halves (packed as uint),
// sums in fp32, RMSNorm(q)+group quant, RMSNorm(kv), k_pe.
// ---------------------------------------------------------------------------
__global__ __launch_bounds__(256) void epilogue_kernel(
    const unsigned short* __restrict__ C0,
    const unsigned short* __restrict__ C1,
    const float* __restrict__ qw,
    const float* __restrict__ kvw,
    float* __restrict__ out)
{
    const size_t OQ   = 0;
    const size_t OS   = (size_t)M_DIM * NQ;
    const size_t OKV  = OS + (size_t)M_DIM * NGROUPS;
    const size_t OKPE = OKV + (size_t)M_DIM * NKV;

    const int row = blockIdx.x;
    const unsigned int* c0 = (const unsigned int*)(C0 + (size_t)row * N_PAD);
    const unsigned int* c1 = (const unsigned int*)(C1 + (size_t)row * N_PAD);
    const int t = threadIdx.x;
    const int lane = t & 63;
    const int wv = t >> 6;

    __shared__ float red1[4], red2[4];

    float qlo[3], qhi[3];
    float ssq = 0.f;
#pragma unroll
    for (int i = 0; i < 3; ++i) {
        const unsigned int a = c0[t + i * 256];
        const unsigned int b = c1[t + i * 256];
        const float lo = __uint_as_float(a << 16) + __uint_as_float(b << 16);
        const float hi = __uint_as_float(a & 0xffff0000u) + __uint_as_float(b & 0xffff0000u);
        qlo[i] = lo; qhi[i] = hi;
        ssq += lo * lo + hi * hi;
    }
    const unsigned int ka = c0[768 + t];
    const unsigned int kb = c1[768 + t];
    const float klo = __uint_as_float(ka << 16) + __uint_as_float(kb << 16);
    const float khi = __uint_as_float(ka & 0xffff0000u) + __uint_as_float(kb & 0xffff0000u);
    float ssk = klo * klo + khi * khi;

#pragma unroll
    for (int off = 32; off; off >>= 1) {
        ssq += __shfl_down(ssq, off);
        ssk += __shfl_down(ssk, off);
    }
    if (lane == 0) { red1[wv] = ssq; red2[wv] = ssk; }
    __syncthreads();
    ssq = red1[0] + red1[1] + red1[2] + red1[3];
    ssk = red2[0] + red2[1] + red2[2] + red2[3];

    const float rsq = rsqrtf(ssq * (1.0f / NQ) + 1e-6f);
    const float rsk = rsqrtf(ssk * (1.0f / NKV) + 1e-6f);

    const float2* qw2  = (const float2*)qw;
    const float2* kvw2 = (const float2*)kvw;

#pragma unroll
    for (int i = 0; i < 3; ++i) {
        const int colp = t + i * 256;
        const float2 w2 = qw2[colp];
        const float a = qlo[i] * rsq * w2.x;
        const float b = qhi[i] * rsq * w2.y;
        float am = fmaxf(fabsf(a), fabsf(b));
#pragma unroll
        for (int off = 32; off; off >>= 1)
            am = fmaxf(am, __shfl_down(am, off));
        am = __shfl(am, 0);
        const float s = fmaxf(am * (1.0f / 448.0f), 1e-12f);
        if (lane == 0) out[OS + (size_t)row * NGROUPS + i * 4 + wv] = s;
        const float rs = 1.0f / s;
        ((float2*)(out + OQ + (size_t)row * NQ))[colp] = make_float2(a * rs, b * rs);
    }

    const float2 kw2 = kvw2[t];
    ((float2*)(out + OKV + (size_t)row * NKV))[t] =
        make_float2(klo * rsk * kw2.x, khi * rsk * kw2.y);

    if (t < NPE / 2) {
        const unsigned int pa = c0[1024 + t];
        const unsigned int pb = c1[1024 + t];
        ((float2*)(out + OKPE + (size_t)row * NPE))[t] = make_float2(
            __uint_as_float(pa << 16) + __uint_as_float(pb << 16),
            __uint_as_float(pa & 0xffff0000u) + __uint_as_float(pb & 0xffff0000u));
    }
}

// ---------------------------------------------------------------------------
extern "C" void kernel_launch(void* const* d_in, const int* in_sizes, int n_in,
                              void* d_out, int out_size, void* d_ws, size_t ws_size,
                              hipStream_t stream)
{
    const float* hs  = (const float*)d_in[0];   // [8192][7168]
    const float* w   = (const float*)d_in[1];   // [7168][2112]
    const float* qw  = (const float*)d_in[2];   // [1536]
    const float* kvw = (const float*)d_in[3];   // [512]
    float* out = (float*)d_out;

    char* ws = (char*)d_ws;
    const size_t A_BYTES  = (size_t)M_DIM * K_DIM * 2;   // 117,440,512
    const size_t BT_BYTES = (size_t)N_DIM * K_DIM * 2;   //  30,277,632
    unsigned short* Abf = (unsigned short*)ws;
    unsigned short* Bt  = (unsigned short*)(ws + A_BYTES);
    unsigned short* C   = (unsigned short*)(ws + A_BYTES + BT_BYTES);
    unsigned short* C0  = C;
    unsigned short* C1  = C + (size_t)M_DIM * N_PAD;

    // 1) A fp32 -> bf16
    cvt_a_kernel<<<8192, 256, 0, stream>>>(hs, Abf, (M_DIM * K_DIM) / 4);

    // 2) W -> Bt (transpose + convert)
    dim3 gt(N_DIM / 32, K_DIM / 64);
    cvt_bt_kernel<<<gt, 256, 0, stream>>>(w, Bt);

    // 3) GEMM, high-TLP small-block schedule, split-K=2
    gemm8_kernel<<<NWG, 256, 0, stream>>>(Abf, Bt, C);

    // 4) epilogue
    epilogue_kernel<<<M_DIM, 256, 0, stream>>>(C0, C1, qw, kvw, out);
}